// Round 9
// baseline (169.318 us; speedup 1.0000x reference)
//
#include <hip/hip_runtime.h>

typedef _Float16 f16;
typedef __fp16   fp16x2 __attribute__((ext_vector_type(2)));   // cvt_pkrtz return type
typedef _Float16 f16x8 __attribute__((ext_vector_type(8)));
typedef float    f32x4 __attribute__((ext_vector_type(4)));

#define MFMA16(A, B, C) __builtin_amdgcn_mfma_f32_16x16x32_f16((A), (B), (C), 0, 0, 0)

// async 16B global->LDS. dest = wave-uniform base + lane*16; source per-lane.
__device__ __forceinline__ void gl_lds16(const void* g, void* l) {
  __builtin_amdgcn_global_load_lds(
      (const __attribute__((address_space(1))) void*)g,
      (__attribute__((address_space(3))) void*)l, 16, 0, 0);
}

// Workspace layout (bytes).
static constexpr size_t OFF_XH  = 0;                       // X fp16 [8192][512]
static constexpr size_t OFF_WQT = 8388608;                 // QKV B^T stacked [1536][512]
static constexpr size_t OFF_WOT = OFF_WQT + 3 * 524288;
static constexpr size_t OFF_QH  = OFF_WOT + 524288;        // Q fp16 [8192][512] (pre-scaled)
static constexpr size_t OFF_KH  = OFF_QH + 8388608;        // K fp16 [8192][512]
static constexpr size_t OFF_VT  = OFF_KH + 8388608;        // V^T fp16 [4][8][64][2048]
static constexpr size_t OFF_A2  = OFF_VT + 8388608;        // attn out fp16 [8192][512]
static constexpr size_t OFF_AMK = OFF_A2 + 8388608;        // add-mask f32 [4][2048]
static constexpr size_t OFF_VM  = OFF_AMK + 32768;         // vmean f32 [4][8][64]

// log2(e)*0.125 folded into Wq;  8*log2(e) subtracted via MFMA C-init.
#define QSCALE 0.18033688011112042f
#define NEGFIX -11.541560327111708f

// -------- convert x: fp32 -> fp16; also build additive k-mask array --------
__global__ void k_cvt_x(const float* __restrict__ x, f16* __restrict__ xh,
                        const int* __restrict__ mask_k, float* __restrict__ amk) {
  int i = blockIdx.x * blockDim.x + threadIdx.x;
  const float4* p = (const float4*)x + (size_t)i * 2;
  float4 a = p[0], b = p[1];
  f16x8 o = { (f16)a.x, (f16)a.y, (f16)a.z, (f16)a.w,
              (f16)b.x, (f16)b.y, (f16)b.z, (f16)b.w };
  *((f16x8*)xh + i) = o;
  if (i < 8192) amk[i] = mask_k[i] ? 0.0f : -1000.0f;
}

// ---- transpose+convert all 4 weights (z picks which); Wq gets QSCALE folded ----
__global__ void k_cvt_w4(const float* __restrict__ w0, const float* __restrict__ w1,
                         const float* __restrict__ w2, const float* __restrict__ w3,
                         f16* __restrict__ dst) {
  __shared__ float tile[32][33];
  const int z = blockIdx.z;
  const float* w = (z == 0) ? w0 : (z == 1) ? w1 : (z == 2) ? w2 : w3;
  const float sc = (z == 0) ? QSCALE : 1.0f;
  f16* wt = dst + (size_t)z * 262144;
  int tx = threadIdx.x & 31, ty = threadIdx.x >> 5;
  int bx = blockIdx.x, by = blockIdx.y;
#pragma unroll
  for (int i = 0; i < 32; i += 8)
    tile[ty + i][tx] = w[(size_t)(by * 32 + ty + i) * 512 + bx * 32 + tx];
  __syncthreads();
#pragma unroll
  for (int i = 0; i < 32; i += 8)
    wt[(size_t)(bx * 32 + ty + i) * 512 + by * 32 + tx] = (f16)(tile[tx][ty + i] * sc);
}

// -------- vmean[b][h][d] = mean over n of V: one wave per Vt row --------
__global__ void k_vmean(const f16* __restrict__ Vt, float* __restrict__ vm) {
  int row = blockIdx.x * 4 + (threadIdx.x >> 6);   // 512 blocks x 4 waves = 2048 rows
  int lane = threadIdx.x & 63;
  const f16x8* p = (const f16x8*)(Vt + (size_t)row * 2048) + lane;
  float s = 0.f;
#pragma unroll
  for (int i = 0; i < 4; ++i) {
    f16x8 v = p[i * 64];
#pragma unroll
    for (int e = 0; e < 8; ++e) s += (float)v[e];
  }
#pragma unroll
  for (int i = 32; i; i >>= 1) s += __shfl_xor(s, i, 64);
  if (lane == 0) vm[row] = s * (1.0f / 2048.0f);
}

// -------- BMxBN fp16 MFMA GEMM, K=512, BK=64, double-buffered, XCD-swizzled ------
// MODE 2: C fp32 [M][512] + bias (O0)
// MODE 3: fused QKV (BM=BN=128): seg 0->Q f16 (O0), 1->K f16 (O1), 2->V^T (O2)
template <int MODE, int BM, int BN>
__global__ __launch_bounds__(256, (MODE == 2 ? 3 : 2))
void k_gemm(const f16* __restrict__ A, const f16* __restrict__ Bt,
            void* __restrict__ O0, void* __restrict__ O1, void* __restrict__ O2,
            const float* __restrict__ bias) {
  constexpr int MR = BM / 32, NF = BN / 32;
  constexpr int AP = BM / 32, BP = BN / 32;       // 4KB stage issues
  constexpr int ABYTES = BM * 128;
  constexpr int BBYTES = BN * 128;
  constexpr int SM_STAGE  = 2 * (ABYTES + BBYTES);
  constexpr int SM_BOUNCE = (MODE == 3) ? 128 * 136 * 2 : 0;
  constexpr int SM = SM_STAGE > SM_BOUNCE ? SM_STAGE : SM_BOUNCE;
  __shared__ __align__(16) char smem[SM];
  const int t = threadIdx.x;
  const int lane = t & 63, w = t >> 6;
  const int wr = w >> 1, wc = w & 1;
  const int l15 = lane & 15, l4 = lane >> 4;
  const int lr = lane >> 3, lc = lane & 7;
  // XCD-bijective swizzle (grid %8 == 0): contiguous work chunk per XCD
  const int flat = blockIdx.x + gridDim.x * blockIdx.y;
  const int nwg  = gridDim.x * gridDim.y;
  const int sw   = (flat & 7) * (nwg >> 3) + (flat >> 3);
  const int row0 = (sw / gridDim.x) * BM;
  const int col0 = (sw % gridDim.x) * BN;

  f32x4 acc[MR][NF] = {};

  auto stage = [&](int kt, int buf) {
    char* dA = smem + buf * ABYTES + w * 1024;
    char* dB = smem + 2 * ABYTES + buf * BBYTES + w * 1024;
#pragma unroll
    for (int p = 0; p < AP; ++p) {
      int r = p * 32 + w * 8 + lr;
      gl_lds16((const char*)A + ((size_t)(row0 + r) * 512 + kt) * 2 + ((lc ^ (r & 7)) << 4),
               dA + p * 4096);
    }
#pragma unroll
    for (int p = 0; p < BP; ++p) {
      int r = p * 32 + w * 8 + lr;
      gl_lds16((const char*)Bt + ((size_t)(col0 + r) * 512 + kt) * 2 + ((lc ^ (r & 7)) << 4),
               dB + p * 4096);
    }
  };

  stage(0, 0);
  for (int ks = 0; ks < 8; ++ks) {
    const int buf = ks & 1;
    __syncthreads();                            // stage(buf) drained; buf^1 reads done
    if (ks < 7) stage((ks + 1) * 64, buf ^ 1);  // in flight under this compute
    const char* cA = smem + buf * ABYTES;
    const char* cB = smem + 2 * ABYTES + buf * BBYTES;
    __builtin_amdgcn_s_setprio(1);
#pragma unroll
    for (int kb = 0; kb < 2; ++kb) {
      f16x8 af[MR], bf[NF];
#pragma unroll
      for (int m = 0; m < MR; ++m) {
        int r = wr * (BM / 2) + m * 16 + l15;
        int lb = r * 128 + kb * 64 + l4 * 16;
        af[m] = *(const f16x8*)(cA + (lb ^ ((r & 7) << 4)));
      }
#pragma unroll
      for (int n = 0; n < NF; ++n) {
        int r = wc * (BN / 2) + n * 16 + l15;
        int lb = r * 128 + kb * 64 + l4 * 16;
        bf[n] = *(const f16x8*)(cB + (lb ^ ((r & 7) << 4)));
      }
#pragma unroll
      for (int m = 0; m < MR; ++m)
#pragma unroll
        for (int n = 0; n < NF; ++n)
          acc[m][n] = MFMA16(af[m], bf[n], acc[m][n]);
    }
    __builtin_amdgcn_s_setprio(0);
  }

  // ---- epilogue; C frag: col = lane&15, row = (lane>>4)*4 + reg ----
  if (MODE == 2) {
#pragma unroll
    for (int m = 0; m < MR; ++m)
#pragma unroll
      for (int n = 0; n < NF; ++n) {
        int gr = row0 + wr * (BM / 2) + m * 16 + l4 * 4;
        int gc = col0 + wc * (BN / 2) + n * 16 + l15;
        float* C = (float*)O0;
        float bv = bias[gc];
#pragma unroll
        for (int rr = 0; rr < 4; ++rr)
          C[(size_t)(gr + rr) * 512 + gc] = acc[m][n][rr] + bv;
      }
  } else {
    int seg = col0 >> 9;                        // block-uniform
    if (seg < 2) {
      __syncthreads();
      f16* bb = (f16*)smem;                     // [128][136] bounce
#pragma unroll
      for (int m = 0; m < MR; ++m)
#pragma unroll
        for (int n = 0; n < NF; ++n) {
          int r = wr * (BM / 2) + m * 16 + l4 * 4;
          int c = wc * (BN / 2) + n * 16 + l15;
#pragma unroll
          for (int rr = 0; rr < 4; ++rr)
            bb[(r + rr) * 136 + c] = (f16)acc[m][n][rr];
        }
      __syncthreads();
      f16* C = (f16*)(seg == 0 ? O0 : O1);
      int cbase = col0 & 511;
#pragma unroll
      for (int i = 0; i < 8; ++i) {
        int idx = i * 256 + t;
        int r = idx >> 4, c8 = (idx & 15) * 8;
        uint4 v = *(const uint4*)(bb + r * 136 + c8);
        *(uint4*)(C + (size_t)(row0 + r) * 512 + cbase + c8) = v;
      }
    } else {
#pragma unroll
      for (int m = 0; m < MR; ++m)
#pragma unroll
        for (int n = 0; n < NF; ++n) {
          int gr = row0 + wr * (BM / 2) + m * 16 + l4 * 4;
          int lcol = (col0 & 511) + wc * (BN / 2) + n * 16 + l15;
          f16* C = (f16*)O2;
          int hh = lcol >> 6, dd = lcol & 63;
          int bb2 = gr >> 11, ns = gr & 2047;
          union { uint2 u2; f16 v[4]; } pk;
#pragma unroll
          for (int rr = 0; rr < 4; ++rr) pk.v[rr] = (f16)acc[m][n][rr];
          *(uint2*)(C + (size_t)((bb2 * 8 + hh) * 64 + dd) * 2048 + ns) = pk.u2;
        }
    }
  }
}

// ---------- flash attention: swapped QK^T, fixed-max, denom via MFMA ----------
// 4 waves x 32 q; KVBLK=64 double-buffered (48KB LDS -> 3 blocks/CU).
// In-loop softmax: p = exp2(s + amk) only (masked-q handled by vmean epilogue).
__global__ __launch_bounds__(256, 3)
void k_attn(const f16* __restrict__ Q, const f16* __restrict__ K,
            const f16* __restrict__ Vt, const float* __restrict__ amk,
            const int* __restrict__ mask_q, const float* __restrict__ vmean,
            f16* __restrict__ A2) {
  __shared__ __align__(16) f16 sK[2][64 * 64];      // [j][d] 128B rows, swizzled
  __shared__ __align__(16) f16 sV[2][64 * 64];      // [d][j] 128B rows, swizzled
  __shared__ __align__(16) f16 sP[4][32 * 64];      // per-wave [q][j], swizzled
  const int t = threadIdx.x, lane = t & 63, w = t >> 6;
  const int l15 = lane & 15, l4 = lane >> 4;
  const int lr = lane >> 3, lc = lane & 7;
  // XCD swizzle: 16 q-blocks of one (b,h) contiguous per XCD chunk
  const int sw = (blockIdx.x & 7) * 64 + (blockIdx.x >> 3);
  const int qx = sw & 15, bh = sw >> 4;
  const int b = bh >> 3, h = bh & 7;
  const int q0 = qx * 128 + w * 32;

  f16x8 qa[2][2];
#pragma unroll
  for (int g = 0; g < 2; ++g) {
    const f16* qb = Q + (size_t)(b * 2048 + q0 + g * 16 + l15) * 512 + h * 64 + l4 * 8;
    qa[g][0] = *(const f16x8*)qb;
    qa[g][1] = *(const f16x8*)(qb + 32);
  }

  const f16x8 onesv = { (f16)1.f, (f16)1.f, (f16)1.f, (f16)1.f,
                        (f16)1.f, (f16)1.f, (f16)1.f, (f16)1.f };
  f32x4 o[2][4] = {};
  f32x4 oex[2] = {};

  const char* Kbase  = (const char*)K + ((size_t)b * 2048 * 512 + h * 64) * 2;
  const char* VtBase = (const char*)Vt + ((size_t)(b * 8 + h) * 64) * 2048 * 2;
  const float* amkb = amk + b * 2048;
  char* sPw = (char*)&sP[w][0];

  auto stage = [&](int kv, int buf) {
#pragma unroll
    for (int p = 0; p < 2; ++p) {                   // K: 64 rows x 128B
      int r = p * 32 + w * 8 + lr;
      gl_lds16(Kbase + (size_t)(kv + r) * 1024 + ((lc ^ (r & 7)) << 4),
               (char*)&sK[buf][0] + p * 4096 + w * 1024);
    }
#pragma unroll
    for (int p = 0; p < 2; ++p) {                   // V^T: 64 rows x 128B
      int d = p * 32 + w * 8 + lr;
      gl_lds16(VtBase + ((size_t)d * 2048 + kv) * 2 + ((lc ^ (d & 7)) << 4),
               (char*)&sV[buf][0] + p * 4096 + w * 1024);
    }
  };

  stage(0, 0);
  for (int it = 0; it < 32; ++it) {
    const int kv = it * 64, buf = it & 1;
    __syncthreads();                                // buf ready; buf^1 reads done
    if (it < 31) stage(kv + 64, buf ^ 1);           // hides under this tile
    const char* cK = (const char*)&sK[buf][0];
    const char* cV = (const char*)&sV[buf][0];

    f32x4 amv[4];
#pragma unroll
    for (int jf = 0; jf < 4; ++jf)
      amv[jf] = *(const f32x4*)(amkb + kv + jf * 16 + l4 * 4);

    // S^T = K Q^T + NEGFIX: rows j, cols q (swapped operands)
    f32x4 sT[2][4];
    __builtin_amdgcn_s_setprio(1);
#pragma unroll
    for (int jf = 0; jf < 4; ++jf) {
      int r = jf * 16 + l15;
      int base = r * 128 + l4 * 16;
      f16x8 k0 = *(const f16x8*)(cK + (base ^ ((r & 7) << 4)));
      f16x8 k1 = *(const f16x8*)(cK + ((base + 64) ^ ((r & 7) << 4)));
#pragma unroll
      for (int g = 0; g < 2; ++g) {
        f32x4 z = { NEGFIX, NEGFIX, NEGFIX, NEGFIX };
        z = MFMA16(k0, qa[g][0], z);
        z = MFMA16(k1, qa[g][1], z);
        sT[g][jf] = z;
      }
    }
    __builtin_amdgcn_s_setprio(0);

    // p = exp2(s + amk); pack -> one b64 write per (g,jf)
#pragma unroll
    for (int g = 0; g < 2; ++g)
#pragma unroll
      for (int jf = 0; jf < 4; ++jf) {
        float p0 = __builtin_amdgcn_exp2f(sT[g][jf][0] + amv[jf][0]);
        float p1 = __builtin_amdgcn_exp2f(sT[g][jf][1] + amv[jf][1]);
        float p2 = __builtin_amdgcn_exp2f(sT[g][jf][2] + amv[jf][2]);
        float p3 = __builtin_amdgcn_exp2f(sT[g][jf][3] + amv[jf][3]);
        fp16x2 a01 = __builtin_amdgcn_cvt_pkrtz(p0, p1);
        fp16x2 a23 = __builtin_amdgcn_cvt_pkrtz(p2, p3);
        uint2 pk = { __builtin_bit_cast(unsigned, a01),
                     __builtin_bit_cast(unsigned, a23) };
        int row = g * 16 + l15;
        int boff = row * 128 + jf * 32 + l4 * 8;
        *(uint2*)(sPw + (boff ^ ((row & 7) << 4))) = pk;
      }

    // O += P V ; denom += P 1
    __builtin_amdgcn_s_setprio(1);
#pragma unroll
    for (int kb = 0; kb < 2; ++kb) {
      f16x8 pa[2];
#pragma unroll
      for (int g = 0; g < 2; ++g) {
        int rq = g * 16 + l15;
        int pbase = rq * 128 + kb * 64 + l4 * 16;
        pa[g] = *(const f16x8*)(sPw + (pbase ^ ((rq & 7) << 4)));
        oex[g] = MFMA16(pa[g], onesv, oex[g]);
      }
#pragma unroll
      for (int df = 0; df < 4; ++df) {
        int d = df * 16 + l15;
        int vbase = d * 128 + kb * 64 + l4 * 16;
        f16x8 bv = *(const f16x8*)(cV + (vbase ^ ((d & 7) << 4)));
#pragma unroll
        for (int g = 0; g < 2; ++g)
          o[g][df] = MFMA16(pa[g], bv, o[g][df]);
      }
    }
    __builtin_amdgcn_s_setprio(0);
  }

  // epilogue: divide by denom; masked-q rows get vmean (uniform-over-all-j)
#pragma unroll
  for (int g = 0; g < 2; ++g) {
    const int4 mq4 = *(const int4*)(mask_q + b * 2048 + q0 + g * 16 + l4 * 4);
    const int mq[4] = { mq4.x, mq4.y, mq4.z, mq4.w };
    float inv[4];
#pragma unroll
    for (int rr = 0; rr < 4; ++rr) inv[rr] = 1.0f / oex[g][rr];
#pragma unroll
    for (int df = 0; df < 4; ++df) {
      float vm = vmean[(b * 8 + h) * 64 + df * 16 + l15];
#pragma unroll
      for (int rr = 0; rr < 4; ++rr) {
        float val = mq[rr] ? (o[g][df][rr] * inv[rr]) : vm;
        A2[(size_t)(b * 2048 + q0 + g * 16 + l4 * 4 + rr) * 512 + h * 64 + df * 16 + l15] =
            (f16)val;
      }
    }
  }
}

extern "C" void kernel_launch(void* const* d_in, const int* in_sizes, int n_in,
                              void* d_out, int out_size, void* d_ws, size_t ws_size,
                              hipStream_t stream) {
  (void)in_sizes; (void)n_in; (void)out_size; (void)ws_size;
  const float* x   = (const float*)d_in[0];
  const float* Wq  = (const float*)d_in[1];
  const float* Wk  = (const float*)d_in[2];
  const float* Wv  = (const float*)d_in[3];
  const float* Wo  = (const float*)d_in[4];
  const float* bo  = (const float*)d_in[5];
  const int* mask_k = (const int*)d_in[6];
  const int* mask_q = (const int*)d_in[7];
  float* out = (float*)d_out;
  char* ws = (char*)d_ws;

  f16* Xh   = (f16*)(ws + OFF_XH);
  f16* Wqkv = (f16*)(ws + OFF_WQT);
  f16* Wot  = (f16*)(ws + OFF_WOT);
  f16* Qh   = (f16*)(ws + OFF_QH);
  f16* Kh   = (f16*)(ws + OFF_KH);
  f16* Vt   = (f16*)(ws + OFF_VT);
  f16* A2   = (f16*)(ws + OFF_A2);
  float* AMK = (float*)(ws + OFF_AMK);
  float* VM  = (float*)(ws + OFF_VM);

  k_cvt_x<<<2048, 256, 0, stream>>>(x, Xh, mask_k, AMK);
  k_cvt_w4<<<dim3(16, 16, 4), 256, 0, stream>>>(Wq, Wk, Wv, Wo, Wqkv);

  k_gemm<3, 128, 128><<<dim3(12, 64), 256, 0, stream>>>(Xh, Wqkv, Qh, Kh, Vt, nullptr);

  k_vmean<<<512, 256, 0, stream>>>(Vt, VM);

  k_attn<<<512, 256, 0, stream>>>(Qh, Kh, Vt, AMK, mask_q, VM, A2);

  k_gemm<2, 128, 64><<<dim3(8, 64), 256, 0, stream>>>(A2, Wot, out, nullptr, nullptr, bo);
}